// Round 19
// baseline (129.692 us; speedup 1.0000x reference)
//
#include <hip/hip_runtime.h>

#define NN 50000
#define NE 800000
#define EH (NE + NN)   // 850000 edges incl. self-loops
#define HD 128
#define NCH 4          // column chunks
#define CPW 32         // cols per chunk (bf16 row = 64 B = one cache line)
#define PSTRH ((NN + 1) * CPW)  // halves per panel = 1600032 (row NN = dummy zeros)
// window structure: 256-node windows
#define WLOG 8
#define WSZ 256
#define NWIN 196       // ceil(NN/256)
#define NSLOT (NWIN * WSZ)    // 50176 perm slots (window-strided)
#define CAPW 5632      // fixed csr slots per window (mean padded 4736, +13 sigma), %4==0
#define BKTA 256       // bucket slot allocation (196 used)
#define BCAP 5120      // per-bucket capacity (mean 4352, +12 sigma)
#define EPB 4096
#define NBB 208        // ceil(EH/EPB)

typedef __attribute__((ext_vector_type(8))) short bf16x8;
typedef __attribute__((ext_vector_type(4))) float f32x4;
typedef __attribute__((ext_vector_type(4))) unsigned int u32x4;

__device__ __forceinline__ unsigned short f2bf(float f) {
  union { float f; unsigned int u; } v; v.f = f;
  unsigned int r = v.u + 0x7FFFu + ((v.u >> 16) & 1u);   // RNE
  return (unsigned short)(r >> 16);
}
__device__ __forceinline__ unsigned int pack2(float lo, float hi) {
  return (unsigned int)f2bf(lo) | ((unsigned int)f2bf(hi) << 16);
}

// ---------------- phase 1: bucket edges by 256-node window --------------------
// packed edge: src(16b) | dstlo(8b)<<16 | win(8b)<<24
__global__ __launch_bounds__(256) void k_bucket(const int* __restrict__ src,
                                                const int* __restrict__ dst,
                                                int* __restrict__ gcur,
                                                unsigned int* __restrict__ ebuf) {
  __shared__ unsigned int stage[EPB];     // 16 KB
  __shared__ int cnt[256], base[256], lcur[256], gbase[256];
  __shared__ int sTotal;
  const int tid = threadIdx.x;
  const int e0 = blockIdx.x * EPB;
  cnt[tid] = 0;
  __syncthreads();
  unsigned int myv[EPB / 256];
  #pragma unroll
  for (int m = 0; m < EPB / 256; ++m) {
    int e = e0 + m * 256 + tid;
    unsigned int v = 0;
    if (e < EH) {
      int s, d;
      if (e < NE) { s = src[e]; d = dst[e]; }
      else        { s = e - NE; d = s; }
      v = (unsigned int)s | ((unsigned int)(d & (WSZ - 1)) << 16)
        | ((unsigned int)(d >> WLOG) << 24);
      atomicAdd(&cnt[d >> WLOG], 1);
    }
    myv[m] = v;
  }
  __syncthreads();
  const int c = cnt[tid];
  base[tid] = c;
  __syncthreads();
  #pragma unroll
  for (int off = 1; off < 256; off <<= 1) {
    int u = (tid >= off) ? base[tid - off] : 0;
    __syncthreads();
    base[tid] += u;
    __syncthreads();
  }
  if (tid == 255) sTotal = base[255];
  int excl = base[tid] - c;
  __syncthreads();
  base[tid] = excl;
  lcur[tid] = excl;
  gbase[tid] = c ? atomicAdd(&gcur[tid], c) : 0;
  __syncthreads();
  #pragma unroll
  for (int m = 0; m < EPB / 256; ++m) {
    int e = e0 + m * 256 + tid;
    if (e < EH) {
      unsigned int v = myv[m];
      int pos = atomicAdd(&lcur[v >> 24], 1);
      stage[pos] = v;
    }
  }
  __syncthreads();
  const int total = sTotal;
  for (int s = tid; s < total; s += 256) {
    unsigned int v = stage[s];
    int b = v >> 24;
    ebuf[(size_t)b * BCAP + gbase[b] + (s - base[b])] = v;
  }
}

// ------- phase 2 (fused): per-window degree + scan + perm + dis + CSR fill + pad ---
__global__ __launch_bounds__(256) void k_wall(const unsigned int* __restrict__ ebuf,
                                              const int* __restrict__ gcur,
                                              int* __restrict__ row_start,
                                              int* __restrict__ row_end,
                                              float* __restrict__ dis,
                                              int* __restrict__ perm,
                                              unsigned short* __restrict__ csr,
                                              const float* __restrict__ W0,
                                              const float* __restrict__ W1,
                                              unsigned short* __restrict__ wt0,
                                              unsigned short* __restrict__ wt1,
                                              unsigned short* __restrict__ panels) {
  const int b = blockIdx.x, tid = threadIdx.x;
  if (b >= NWIN) {   // ---- wprep tail: 16 blocks = 4096 threads ----
    int t = (b - NWIN) * 256 + tid;
    if (t < NCH * CPW) {
      int pl = t >> 5;
      panels[(size_t)pl * PSTRH + (size_t)NN * CPW + (t & 31)] = 0;
    }
    const float* W = (t < 2048) ? W0 : W1;
    unsigned short* Wt = (t < 2048) ? wt0 : wt1;
    int tt = t & 2047;
    int k = tt >> 4, c0 = (tt & 15) * 8;
    float4 v0 = ((const float4*)W)[(k * HD + c0) >> 2];
    float4 v1 = ((const float4*)W)[((k * HD + c0) >> 2) + 1];
    Wt[(c0 + 0) * HD + k] = f2bf(v0.x);
    Wt[(c0 + 1) * HD + k] = f2bf(v0.y);
    Wt[(c0 + 2) * HD + k] = f2bf(v0.z);
    Wt[(c0 + 3) * HD + k] = f2bf(v0.w);
    Wt[(c0 + 4) * HD + k] = f2bf(v1.x);
    Wt[(c0 + 5) * HD + k] = f2bf(v1.y);
    Wt[(c0 + 6) * HD + k] = f2bf(v1.z);
    Wt[(c0 + 7) * HD + k] = f2bf(v1.w);
    return;
  }
  __shared__ int h[256];        // per-node degree histogram
  __shared__ int sc[256];       // scan workspace
  __shared__ int cnt[64], base[64];
  __shared__ int cur[256];
  h[tid] = 0;
  if (tid < 64) cnt[tid] = 0;
  __syncthreads();
  const int n = gcur[b];
  const unsigned int* eb = ebuf + (size_t)b * BCAP;
  for (int i = tid; i < n; i += 256) atomicAdd(&h[(eb[i] >> 16) & (WSZ - 1)], 1);
  __syncthreads();
  const int node = b * WSZ + tid;
  const bool valid = node < NN;
  const int d = h[tid];
  const int pd = (d + 3) & ~3;
  sc[tid] = pd;
  __syncthreads();
  #pragma unroll
  for (int off = 1; off < 256; off <<= 1) {
    int u = (tid >= off) ? sc[tid - off] : 0;
    __syncthreads();
    sc[tid] += u;
    __syncthreads();
  }
  const int rs = b * CAPW + sc[tid] - pd;
  cur[tid] = rs;
  perm[b * WSZ + tid] = NN;
  if (valid) {
    row_start[node] = rs;
    row_end[node] = rs + pd;
    dis[node] = rsqrtf((float)d);   // deg >= 1 always (self-loop)
  }
  const int dc = d > 63 ? 63 : d;
  int sub = 0;
  if (valid) sub = atomicAdd(&cnt[dc], 1);
  __syncthreads();
  if (tid < 64) {
    int c = cnt[tid], v = c;
    #pragma unroll
    for (int off = 1; off < 64; off <<= 1) {
      int u = __shfl_up(v, off);
      if (tid >= off) v += u;
    }
    base[tid] = v - c;
  }
  __syncthreads();
  if (valid) perm[b * WSZ + base[dc] + sub] = node;
  for (int i = tid; i < n; i += 256) {
    unsigned int v = eb[i];
    int pos = atomicAdd(&cur[(v >> 16) & (WSZ - 1)], 1);
    csr[pos] = (unsigned short)(v & 0xFFFFu);
  }
  __syncthreads();
  if (valid) {
    const int e = rs + pd;
    for (int q = cur[tid]; q < e; ++q) csr[q] = (unsigned short)NN;
  }
}

// ------- MFMA GEMM: Cpanels(bf16) = dis[row] * (A[NN,128] @ W) --------------------
#define GR 128
template<bool ABF16>
__global__ __launch_bounds__(256, 2) void k_gemm(const void* __restrict__ Ain,
                                                 const unsigned short* __restrict__ Wt,
                                                 const float* __restrict__ dis,
                                                 unsigned short* __restrict__ C) {
  __shared__ unsigned short Als[GR * HD];   // 32 KB, [row][k] swizzled
  __shared__ unsigned short Bls[HD * HD];   // 32 KB, [col][k] swizzled
  const int tid = threadIdx.x;
  const int r0 = blockIdx.x * GR;
  #pragma unroll
  for (int m = 0; m < 8; ++m) {
    int f = tid + m * 256;
    int row = f >> 4, j = f & 15;       // j = k/8
    int grow = r0 + row;
    uint4 u = make_uint4(0, 0, 0, 0);
    if (grow < NN) {
      if constexpr (ABF16) {
        u = ((const uint4*)Ain)[grow * 16 + j];
      } else {
        const float* A = (const float*)Ain;
        float4 v0 = ((const float4*)A)[grow * 32 + j * 2];
        float4 v1 = ((const float4*)A)[grow * 32 + j * 2 + 1];
        u.x = pack2(v0.x, v0.y); u.y = pack2(v0.z, v0.w);
        u.z = pack2(v1.x, v1.y); u.w = pack2(v1.z, v1.w);
      }
    }
    int slot = j ^ (row & 7);
    *(uint4*)&Als[row * HD + slot * 8] = u;
  }
  #pragma unroll
  for (int m = 0; m < 8; ++m) {
    int f = tid + m * 256;
    int c = f >> 4, j = f & 15;
    uint4 w = ((const uint4*)Wt)[f];
    int slot = j ^ (c & 7);
    *(uint4*)&Bls[c * HD + slot * 8] = w;
  }
  __syncthreads();

  const int w = tid >> 6, l = tid & 63;
  const int lm = l & 15, lg = l >> 4;
  const int rbase = w * 32;
  f32x4 acc[2][8] = {};
  #pragma unroll
  for (int ks = 0; ks < 4; ++ks) {
    int row0 = rbase + lm;
    int row1 = row0 + 16;
    bf16x8 a0 = *(const bf16x8*)&Als[row0 * HD + ((ks * 4 + lg) ^ (row0 & 7)) * 8];
    bf16x8 a1 = *(const bf16x8*)&Als[row1 * HD + ((ks * 4 + lg) ^ (row1 & 7)) * 8];
    #pragma unroll
    for (int ct = 0; ct < 8; ++ct) {
      int c = ct * 16 + lm;
      bf16x8 b = *(const bf16x8*)&Bls[c * HD + ((ks * 4 + lg) ^ (c & 7)) * 8];
      acc[0][ct] = __builtin_amdgcn_mfma_f32_16x16x32_bf16(a0, b, acc[0][ct], 0, 0, 0);
      acc[1][ct] = __builtin_amdgcn_mfma_f32_16x16x32_bf16(a1, b, acc[1][ct], 0, 0, 0);
    }
  }
  #pragma unroll
  for (int rt = 0; rt < 2; ++rt) {
    #pragma unroll
    for (int reg = 0; reg < 4; ++reg) {
      int row = r0 + rbase + rt * 16 + lg * 4 + reg;
      if (row < NN) {
        float dsc = dis[row];
        #pragma unroll
        for (int ct = 0; ct < 8; ++ct) {
          int col = ct * 16 + lm;
          C[(size_t)(col >> 5) * PSTRH + (size_t)row * CPW + (col & 31)] =
              f2bf(acc[rt][ct][reg] * dsc);
        }
      }
    }
  }
}

// ---------------- CSR gather-aggregate (software-pipelined, 2-ahead) --------------
// Loads cached (R15: NT loads regress). Output stores NT (R17 win). NEW: 2-ahead
// software pipeline at 4-edge granularity — batch k's gathers issue 2 iterations
// before their bacc, separating load from use by ~270 cy > ~200 cy L2 latency.
__device__ __forceinline__ void bacc(float* a, uint4 q) {
  union { unsigned int u; float f; } t;
  t.u = q.x << 16;          a[0] += t.f;
  t.u = q.x & 0xFFFF0000u;  a[1] += t.f;
  t.u = q.y << 16;          a[2] += t.f;
  t.u = q.y & 0xFFFF0000u;  a[3] += t.f;
  t.u = q.z << 16;          a[4] += t.f;
  t.u = q.z & 0xFFFF0000u;  a[5] += t.f;
  t.u = q.w << 16;          a[6] += t.f;
  t.u = q.w & 0xFFFF0000u;  a[7] += t.f;
}

template<bool OBF16>
__global__ __launch_bounds__(256) void k_agg(const unsigned short* __restrict__ Tpanels,
                                             const float* __restrict__ dis,
                                             const int* __restrict__ row_start,
                                             const int* __restrict__ row_end,
                                             const unsigned short* __restrict__ csr,
                                             const int* __restrict__ perm,
                                             const float* __restrict__ bias,
                                             void* __restrict__ outv) {
  const int tid = threadIdx.x;
  const int chunk = blockIdx.x & (NCH - 1);
  const int idx = (blockIdx.x >> 2) * 64 + (tid >> 2);
  const int n = perm[idx];
  if (n >= NN) return;                          // unused window-slot
  const int c8 = tid & 3;                       // 8-col slot within chunk
  const unsigned short* __restrict__ P = Tpanels + (size_t)chunk * PSTRH;
  const ushort4* __restrict__ csr4 = (const ushort4*)csr;

  const int jb = row_start[n] >> 2, je = row_end[n] >> 2;   // 4-edge units, >= 1
  float a0[8] = {0,0,0,0,0,0,0,0};
  float a1[8] = {0,0,0,0,0,0,0,0};

  #define LDROW(sx) (*(const uint4*)&P[(size_t)(sx) * CPW + c8 * 8])

  // stage 1 (always exists: deg >= 1)
  ushort4 s = csr4[jb];
  uint4 p0 = LDROW(s.x), p1 = LDROW(s.y), p2 = LDROW(s.z), p3 = LDROW(s.w);
  uint4 q0, q1, q2, q3;
  const bool two = (jb + 1 < je);
  if (two) {
    s = csr4[jb + 1];
    q0 = LDROW(s.x); q1 = LDROW(s.y); q2 = LDROW(s.z); q3 = LDROW(s.w);
  }
  for (int j = jb + 2; j < je; ++j) {
    s = csr4[j];
    uint4 r0 = LDROW(s.x), r1 = LDROW(s.y), r2 = LDROW(s.z), r3 = LDROW(s.w);
    bacc(a0, p0); bacc(a1, p1); bacc(a0, p2); bacc(a1, p3);
    p0 = q0; p1 = q1; p2 = q2; p3 = q3;
    q0 = r0; q1 = r1; q2 = r2; q3 = r3;
  }
  bacc(a0, p0); bacc(a1, p1); bacc(a0, p2); bacc(a1, p3);
  if (two) { bacc(a0, q0); bacc(a1, q1); bacc(a0, q2); bacc(a1, q3); }
  #undef LDROW

  const float dn = dis[n];
  const int cb = chunk * CPW + c8 * 8;
  const float4 b0 = *(const float4*)&bias[cb];
  const float4 b1 = *(const float4*)&bias[cb + 4];
  float r[8];
  #pragma unroll
  for (int i = 0; i < 8; ++i) r[i] = (a0[i] + a1[i]) * dn;
  r[0] += b0.x; r[1] += b0.y; r[2] += b0.z; r[3] += b0.w;
  r[4] += b1.x; r[5] += b1.y; r[6] += b1.z; r[7] += b1.w;
  #pragma unroll
  for (int i = 0; i < 8; ++i) r[i] = (r[i] >= 0.f) ? r[i] : 0.01f * r[i];
  if constexpr (OBF16) {
    u32x4 o;
    o.x = pack2(r[0], r[1]); o.y = pack2(r[2], r[3]);
    o.z = pack2(r[4], r[5]); o.w = pack2(r[6], r[7]);
    __builtin_nontemporal_store(o, (u32x4*)((unsigned short*)outv + (size_t)n * HD + cb));
  } else {
    float* o = (float*)outv + (size_t)n * HD + cb;
    f32x4 r0v = {r[0], r[1], r[2], r[3]};
    f32x4 r1v = {r[4], r[5], r[6], r[7]};
    __builtin_nontemporal_store(r0v, (f32x4*)o);
    __builtin_nontemporal_store(r1v, (f32x4*)(o + 4));
  }
}

extern "C" void kernel_launch(void* const* d_in, const int* in_sizes, int n_in,
                              void* d_out, int out_size, void* d_ws, size_t ws_size,
                              hipStream_t stream) {
  const float* x  = (const float*)d_in[0];
  const int*   ei = (const int*)d_in[1];
  const float* W0 = (const float*)d_in[2];
  const float* b0 = (const float*)d_in[3];
  const float* W1 = (const float*)d_in[4];
  const float* b1 = (const float*)d_in[5];
  float* out = (float*)d_out;
  const int* src = ei;        // edge_index[0] = message source
  const int* dst = ei + NE;   // edge_index[1] = aggregation target

  char* p = (char*)d_ws;
  float* dis       = (float*)p;  p += 50048 * 4;
  int*   row_start = (int*)p;    p += 50048 * 4;
  int*   row_end   = (int*)p;    p += 50048 * 4;
  int*   perm      = (int*)p;    p += NSLOT * 4;        // 50176
  int*   gcur      = (int*)p;    p += 256 * 4;
  unsigned short* csr = (unsigned short*)p; p += (size_t)NWIN * CAPW * 2 + 128;  // 2.2 MB
  unsigned int* ebuf = (unsigned int*)p; p += (size_t)BKTA * BCAP * 4;  // 5.24 MB
  unsigned short* wt0 = (unsigned short*)p; p += 16384 * 2;
  unsigned short* wt1 = (unsigned short*)p; p += 16384 * 2;
  unsigned short* h1  = (unsigned short*)p; p += (size_t)NN * HD * 2;  // bf16 h, 12.8 MB
  unsigned short* bufA = (unsigned short*)p;  // 4 panels x 1600032 halves (~12.8 MB)

  // ---- graph build: 2 kernels + 1 memset ----
  hipMemsetAsync(gcur, 0, 256 * 4, stream);
  k_bucket<<<NBB, 256, 0, stream>>>(src, dst, gcur, ebuf);
  k_wall<<<NWIN + 16, 256, 0, stream>>>(ebuf, gcur, row_start, row_end, dis, perm,
                                        csr, W0, W1, wt0, wt1, bufA);

  const int AGG_GRID = NCH * (NSLOT / 64);   // 4 * 784 = 3136 blocks
  // layer 1: h1(bf16) = leaky(agg(gemm(x,W0)) + b0)
  k_gemm<false><<<(NN + GR - 1) / GR, 256, 0, stream>>>(x, wt0, dis, bufA);
  k_agg<true><<<AGG_GRID, 256, 0, stream>>>(bufA, dis, row_start, row_end, csr, perm, b0, h1);
  // layer 2: out(f32)
  k_gemm<true><<<(NN + GR - 1) / GR, 256, 0, stream>>>(h1, wt1, dis, bufA);
  k_agg<false><<<AGG_GRID, 256, 0, stream>>>(bufA, dis, row_start, row_end, csr, perm, b1, out);
}

// Round 20
// 124.592 us; speedup vs baseline: 1.0409x; 1.0409x over previous
//
#include <hip/hip_runtime.h>

#define NN 50000
#define NE 800000
#define EH (NE + NN)   // 850000 edges incl. self-loops
#define HD 128
#define NCH 4          // column chunks
#define CPW 32         // cols per chunk (bf16 row = 64 B = one cache line)
#define PSTRH ((NN + 1) * CPW)  // halves per panel = 1600032 (row NN = dummy zeros)
// window structure: 256-node windows
#define WLOG 8
#define WSZ 256
#define NWIN 196       // ceil(NN/256)
#define NSLOT (NWIN * WSZ)    // 50176 perm slots (window-strided)
#define CAPW 5632      // fixed csr slots per window (mean padded 4736, +13 sigma), %4==0
#define BKTA 256       // bucket slot allocation (196 used)
#define BCAP 5120      // per-bucket capacity (mean 4352, +12 sigma)
#define EPB 4096
#define NBB 208        // ceil(EH/EPB)

typedef __attribute__((ext_vector_type(8))) short bf16x8;
typedef __attribute__((ext_vector_type(4))) float f32x4;
typedef __attribute__((ext_vector_type(4))) unsigned int u32x4;

__device__ __forceinline__ unsigned short f2bf(float f) {
  union { float f; unsigned int u; } v; v.f = f;
  unsigned int r = v.u + 0x7FFFu + ((v.u >> 16) & 1u);   // RNE
  return (unsigned short)(r >> 16);
}
__device__ __forceinline__ unsigned int pack2(float lo, float hi) {
  return (unsigned int)f2bf(lo) | ((unsigned int)f2bf(hi) << 16);
}

// ---------------- phase 1: bucket edges by 256-node window --------------------
// packed edge: src(16b) | dstlo(8b)<<16 | win(8b)<<24
__global__ __launch_bounds__(256) void k_bucket(const int* __restrict__ src,
                                                const int* __restrict__ dst,
                                                int* __restrict__ gcur,
                                                unsigned int* __restrict__ ebuf) {
  __shared__ unsigned int stage[EPB];     // 16 KB
  __shared__ int cnt[256], base[256], lcur[256], gbase[256];
  __shared__ int sTotal;
  const int tid = threadIdx.x;
  const int e0 = blockIdx.x * EPB;
  cnt[tid] = 0;
  __syncthreads();
  unsigned int myv[EPB / 256];
  #pragma unroll
  for (int m = 0; m < EPB / 256; ++m) {
    int e = e0 + m * 256 + tid;
    unsigned int v = 0;
    if (e < EH) {
      int s, d;
      if (e < NE) { s = src[e]; d = dst[e]; }
      else        { s = e - NE; d = s; }
      v = (unsigned int)s | ((unsigned int)(d & (WSZ - 1)) << 16)
        | ((unsigned int)(d >> WLOG) << 24);
      atomicAdd(&cnt[d >> WLOG], 1);
    }
    myv[m] = v;
  }
  __syncthreads();
  const int c = cnt[tid];
  base[tid] = c;
  __syncthreads();
  #pragma unroll
  for (int off = 1; off < 256; off <<= 1) {
    int u = (tid >= off) ? base[tid - off] : 0;
    __syncthreads();
    base[tid] += u;
    __syncthreads();
  }
  if (tid == 255) sTotal = base[255];
  int excl = base[tid] - c;
  __syncthreads();
  base[tid] = excl;
  lcur[tid] = excl;
  gbase[tid] = c ? atomicAdd(&gcur[tid], c) : 0;
  __syncthreads();
  #pragma unroll
  for (int m = 0; m < EPB / 256; ++m) {
    int e = e0 + m * 256 + tid;
    if (e < EH) {
      unsigned int v = myv[m];
      int pos = atomicAdd(&lcur[v >> 24], 1);
      stage[pos] = v;
    }
  }
  __syncthreads();
  const int total = sTotal;
  for (int s = tid; s < total; s += 256) {
    unsigned int v = stage[s];
    int b = v >> 24;
    ebuf[(size_t)b * BCAP + gbase[b] + (s - base[b])] = v;
  }
}

// ------- phase 2 (fused): per-window degree + scan + perm + dis + CSR fill + pad ---
__global__ __launch_bounds__(256) void k_wall(const unsigned int* __restrict__ ebuf,
                                              const int* __restrict__ gcur,
                                              int* __restrict__ row_start,
                                              int* __restrict__ row_end,
                                              float* __restrict__ dis,
                                              int* __restrict__ perm,
                                              unsigned short* __restrict__ csr,
                                              const float* __restrict__ W0,
                                              const float* __restrict__ W1,
                                              unsigned short* __restrict__ wt0,
                                              unsigned short* __restrict__ wt1,
                                              unsigned short* __restrict__ panels) {
  const int b = blockIdx.x, tid = threadIdx.x;
  if (b >= NWIN) {   // ---- wprep tail: 16 blocks = 4096 threads ----
    int t = (b - NWIN) * 256 + tid;
    if (t < NCH * CPW) {
      int pl = t >> 5;
      panels[(size_t)pl * PSTRH + (size_t)NN * CPW + (t & 31)] = 0;
    }
    const float* W = (t < 2048) ? W0 : W1;
    unsigned short* Wt = (t < 2048) ? wt0 : wt1;
    int tt = t & 2047;
    int k = tt >> 4, c0 = (tt & 15) * 8;
    float4 v0 = ((const float4*)W)[(k * HD + c0) >> 2];
    float4 v1 = ((const float4*)W)[((k * HD + c0) >> 2) + 1];
    Wt[(c0 + 0) * HD + k] = f2bf(v0.x);
    Wt[(c0 + 1) * HD + k] = f2bf(v0.y);
    Wt[(c0 + 2) * HD + k] = f2bf(v0.z);
    Wt[(c0 + 3) * HD + k] = f2bf(v0.w);
    Wt[(c0 + 4) * HD + k] = f2bf(v1.x);
    Wt[(c0 + 5) * HD + k] = f2bf(v1.y);
    Wt[(c0 + 6) * HD + k] = f2bf(v1.z);
    Wt[(c0 + 7) * HD + k] = f2bf(v1.w);
    return;
  }
  __shared__ int h[256];        // per-node degree histogram
  __shared__ int sc[256];       // scan workspace
  __shared__ int cnt[64], base[64];
  __shared__ int cur[256];
  h[tid] = 0;
  if (tid < 64) cnt[tid] = 0;
  __syncthreads();
  const int n = gcur[b];
  const unsigned int* eb = ebuf + (size_t)b * BCAP;
  for (int i = tid; i < n; i += 256) atomicAdd(&h[(eb[i] >> 16) & (WSZ - 1)], 1);
  __syncthreads();
  const int node = b * WSZ + tid;
  const bool valid = node < NN;
  const int d = h[tid];
  const int pd = (d + 3) & ~3;
  sc[tid] = pd;
  __syncthreads();
  #pragma unroll
  for (int off = 1; off < 256; off <<= 1) {
    int u = (tid >= off) ? sc[tid - off] : 0;
    __syncthreads();
    sc[tid] += u;
    __syncthreads();
  }
  const int rs = b * CAPW + sc[tid] - pd;
  cur[tid] = rs;
  perm[b * WSZ + tid] = NN;
  if (valid) {
    row_start[node] = rs;
    row_end[node] = rs + pd;
    dis[node] = rsqrtf((float)d);   // deg >= 1 always (self-loop)
  }
  const int dc = d > 63 ? 63 : d;
  int sub = 0;
  if (valid) sub = atomicAdd(&cnt[dc], 1);
  __syncthreads();
  if (tid < 64) {
    int c = cnt[tid], v = c;
    #pragma unroll
    for (int off = 1; off < 64; off <<= 1) {
      int u = __shfl_up(v, off);
      if (tid >= off) v += u;
    }
    base[tid] = v - c;
  }
  __syncthreads();
  if (valid) perm[b * WSZ + base[dc] + sub] = node;
  for (int i = tid; i < n; i += 256) {
    unsigned int v = eb[i];
    int pos = atomicAdd(&cur[(v >> 16) & (WSZ - 1)], 1);
    csr[pos] = (unsigned short)(v & 0xFFFFu);
  }
  __syncthreads();
  if (valid) {
    const int e = rs + pd;
    for (int q = cur[tid]; q < e; ++q) csr[q] = (unsigned short)NN;
  }
}

// ------- MFMA GEMM: Cpanels(bf16) = dis[row] * (A[NN,128] @ W) --------------------
#define GR 128
template<bool ABF16>
__global__ __launch_bounds__(256, 2) void k_gemm(const void* __restrict__ Ain,
                                                 const unsigned short* __restrict__ Wt,
                                                 const float* __restrict__ dis,
                                                 unsigned short* __restrict__ C) {
  __shared__ unsigned short Als[GR * HD];   // 32 KB, [row][k] swizzled
  __shared__ unsigned short Bls[HD * HD];   // 32 KB, [col][k] swizzled
  const int tid = threadIdx.x;
  const int r0 = blockIdx.x * GR;
  #pragma unroll
  for (int m = 0; m < 8; ++m) {
    int f = tid + m * 256;
    int row = f >> 4, j = f & 15;       // j = k/8
    int grow = r0 + row;
    uint4 u = make_uint4(0, 0, 0, 0);
    if (grow < NN) {
      if constexpr (ABF16) {
        u = ((const uint4*)Ain)[grow * 16 + j];
      } else {
        const float* A = (const float*)Ain;
        float4 v0 = ((const float4*)A)[grow * 32 + j * 2];
        float4 v1 = ((const float4*)A)[grow * 32 + j * 2 + 1];
        u.x = pack2(v0.x, v0.y); u.y = pack2(v0.z, v0.w);
        u.z = pack2(v1.x, v1.y); u.w = pack2(v1.z, v1.w);
      }
    }
    int slot = j ^ (row & 7);
    *(uint4*)&Als[row * HD + slot * 8] = u;
  }
  #pragma unroll
  for (int m = 0; m < 8; ++m) {
    int f = tid + m * 256;
    int c = f >> 4, j = f & 15;
    uint4 w = ((const uint4*)Wt)[f];
    int slot = j ^ (c & 7);
    *(uint4*)&Bls[c * HD + slot * 8] = w;
  }
  __syncthreads();

  const int w = tid >> 6, l = tid & 63;
  const int lm = l & 15, lg = l >> 4;
  const int rbase = w * 32;
  f32x4 acc[2][8] = {};
  #pragma unroll
  for (int ks = 0; ks < 4; ++ks) {
    int row0 = rbase + lm;
    int row1 = row0 + 16;
    bf16x8 a0 = *(const bf16x8*)&Als[row0 * HD + ((ks * 4 + lg) ^ (row0 & 7)) * 8];
    bf16x8 a1 = *(const bf16x8*)&Als[row1 * HD + ((ks * 4 + lg) ^ (row1 & 7)) * 8];
    #pragma unroll
    for (int ct = 0; ct < 8; ++ct) {
      int c = ct * 16 + lm;
      bf16x8 b = *(const bf16x8*)&Bls[c * HD + ((ks * 4 + lg) ^ (c & 7)) * 8];
      acc[0][ct] = __builtin_amdgcn_mfma_f32_16x16x32_bf16(a0, b, acc[0][ct], 0, 0, 0);
      acc[1][ct] = __builtin_amdgcn_mfma_f32_16x16x32_bf16(a1, b, acc[1][ct], 0, 0, 0);
    }
  }
  #pragma unroll
  for (int rt = 0; rt < 2; ++rt) {
    #pragma unroll
    for (int reg = 0; reg < 4; ++reg) {
      int row = r0 + rbase + rt * 16 + lg * 4 + reg;
      if (row < NN) {
        float dsc = dis[row];
        #pragma unroll
        for (int ct = 0; ct < 8; ++ct) {
          int col = ct * 16 + lm;
          C[(size_t)(col >> 5) * PSTRH + (size_t)row * CPW + (col & 31)] =
              f2bf(acc[rt][ct][reg] * dsc);
        }
      }
    }
  }
}

// ---------------- CSR gather-aggregate (bf16 panels, u16 csr, window-sorted) ------
// Loads cached (R15: NT loads regress). Output stores NT (R17 win). Plain 8-deep
// unrolled loop (R19 proved pipelining is neutral: L2 random-request floor).
__device__ __forceinline__ void bacc(float* a, uint4 q) {
  union { unsigned int u; float f; } t;
  t.u = q.x << 16;          a[0] += t.f;
  t.u = q.x & 0xFFFF0000u;  a[1] += t.f;
  t.u = q.y << 16;          a[2] += t.f;
  t.u = q.y & 0xFFFF0000u;  a[3] += t.f;
  t.u = q.z << 16;          a[4] += t.f;
  t.u = q.z & 0xFFFF0000u;  a[5] += t.f;
  t.u = q.w << 16;          a[6] += t.f;
  t.u = q.w & 0xFFFF0000u;  a[7] += t.f;
}

template<bool OBF16>
__global__ __launch_bounds__(256) void k_agg(const unsigned short* __restrict__ Tpanels,
                                             const float* __restrict__ dis,
                                             const int* __restrict__ row_start,
                                             const int* __restrict__ row_end,
                                             const unsigned short* __restrict__ csr,
                                             const int* __restrict__ perm,
                                             const float* __restrict__ bias,
                                             void* __restrict__ outv) {
  const int tid = threadIdx.x;
  const int chunk = blockIdx.x & (NCH - 1);
  const int idx = (blockIdx.x >> 2) * 64 + (tid >> 2);
  const int n = perm[idx];
  if (n >= NN) return;                          // unused window-slot
  const int c8 = tid & 3;                       // 8-col slot within chunk
  const unsigned short* __restrict__ P = Tpanels + (size_t)chunk * PSTRH;
  const ushort4* __restrict__ csr4 = (const ushort4*)csr;

  const int jb = row_start[n] >> 2, je = row_end[n] >> 2;   // 4-aligned
  float a0[8] = {0,0,0,0,0,0,0,0};
  float a1[8] = {0,0,0,0,0,0,0,0};
  int j = jb;
  for (; j + 2 <= je; j += 2) {
    ushort4 sA = csr4[j], sB = csr4[j + 1];
    uint4 q0 = *(const uint4*)&P[(size_t)sA.x * CPW + c8 * 8];
    uint4 q1 = *(const uint4*)&P[(size_t)sA.y * CPW + c8 * 8];
    uint4 q2 = *(const uint4*)&P[(size_t)sA.z * CPW + c8 * 8];
    uint4 q3 = *(const uint4*)&P[(size_t)sA.w * CPW + c8 * 8];
    uint4 q4 = *(const uint4*)&P[(size_t)sB.x * CPW + c8 * 8];
    uint4 q5 = *(const uint4*)&P[(size_t)sB.y * CPW + c8 * 8];
    uint4 q6 = *(const uint4*)&P[(size_t)sB.z * CPW + c8 * 8];
    uint4 q7 = *(const uint4*)&P[(size_t)sB.w * CPW + c8 * 8];
    bacc(a0, q0); bacc(a1, q1); bacc(a0, q2); bacc(a1, q3);
    bacc(a0, q4); bacc(a1, q5); bacc(a0, q6); bacc(a1, q7);
  }
  if (j < je) {
    ushort4 sA = csr4[j];
    uint4 q0 = *(const uint4*)&P[(size_t)sA.x * CPW + c8 * 8];
    uint4 q1 = *(const uint4*)&P[(size_t)sA.y * CPW + c8 * 8];
    uint4 q2 = *(const uint4*)&P[(size_t)sA.z * CPW + c8 * 8];
    uint4 q3 = *(const uint4*)&P[(size_t)sA.w * CPW + c8 * 8];
    bacc(a0, q0); bacc(a1, q1); bacc(a0, q2); bacc(a1, q3);
  }
  const float dn = dis[n];
  const int cb = chunk * CPW + c8 * 8;
  const float4 b0 = *(const float4*)&bias[cb];
  const float4 b1 = *(const float4*)&bias[cb + 4];
  float r[8];
  #pragma unroll
  for (int i = 0; i < 8; ++i) r[i] = (a0[i] + a1[i]) * dn;
  r[0] += b0.x; r[1] += b0.y; r[2] += b0.z; r[3] += b0.w;
  r[4] += b1.x; r[5] += b1.y; r[6] += b1.z; r[7] += b1.w;
  #pragma unroll
  for (int i = 0; i < 8; ++i) r[i] = (r[i] >= 0.f) ? r[i] : 0.01f * r[i];
  if constexpr (OBF16) {
    u32x4 o;
    o.x = pack2(r[0], r[1]); o.y = pack2(r[2], r[3]);
    o.z = pack2(r[4], r[5]); o.w = pack2(r[6], r[7]);
    __builtin_nontemporal_store(o, (u32x4*)((unsigned short*)outv + (size_t)n * HD + cb));
  } else {
    float* o = (float*)outv + (size_t)n * HD + cb;
    f32x4 r0v = {r[0], r[1], r[2], r[3]};
    f32x4 r1v = {r[4], r[5], r[6], r[7]};
    __builtin_nontemporal_store(r0v, (f32x4*)o);
    __builtin_nontemporal_store(r1v, (f32x4*)(o + 4));
  }
}

extern "C" void kernel_launch(void* const* d_in, const int* in_sizes, int n_in,
                              void* d_out, int out_size, void* d_ws, size_t ws_size,
                              hipStream_t stream) {
  const float* x  = (const float*)d_in[0];
  const int*   ei = (const int*)d_in[1];
  const float* W0 = (const float*)d_in[2];
  const float* b0 = (const float*)d_in[3];
  const float* W1 = (const float*)d_in[4];
  const float* b1 = (const float*)d_in[5];
  float* out = (float*)d_out;
  const int* src = ei;        // edge_index[0] = message source
  const int* dst = ei + NE;   // edge_index[1] = aggregation target

  char* p = (char*)d_ws;
  float* dis       = (float*)p;  p += 50048 * 4;
  int*   row_start = (int*)p;    p += 50048 * 4;
  int*   row_end   = (int*)p;    p += 50048 * 4;
  int*   perm      = (int*)p;    p += NSLOT * 4;        // 50176
  int*   gcur      = (int*)p;    p += 256 * 4;
  unsigned short* csr = (unsigned short*)p; p += (size_t)NWIN * CAPW * 2 + 128;  // 2.2 MB
  unsigned int* ebuf = (unsigned int*)p; p += (size_t)BKTA * BCAP * 4;  // 5.24 MB
  unsigned short* wt0 = (unsigned short*)p; p += 16384 * 2;
  unsigned short* wt1 = (unsigned short*)p; p += 16384 * 2;
  unsigned short* h1  = (unsigned short*)p; p += (size_t)NN * HD * 2;  // bf16 h, 12.8 MB
  unsigned short* bufA = (unsigned short*)p;  // 4 panels x 1600032 halves (~12.8 MB)

  // ---- graph build: 2 kernels + 1 memset ----
  hipMemsetAsync(gcur, 0, 256 * 4, stream);
  k_bucket<<<NBB, 256, 0, stream>>>(src, dst, gcur, ebuf);
  k_wall<<<NWIN + 16, 256, 0, stream>>>(ebuf, gcur, row_start, row_end, dis, perm,
                                        csr, W0, W1, wt0, wt1, bufA);

  const int AGG_GRID = NCH * (NSLOT / 64);   // 4 * 784 = 3136 blocks
  // layer 1: h1(bf16) = leaky(agg(gemm(x,W0)) + b0)
  k_gemm<false><<<(NN + GR - 1) / GR, 256, 0, stream>>>(x, wt0, dis, bufA);
  k_agg<true><<<AGG_GRID, 256, 0, stream>>>(bufA, dis, row_start, row_end, csr, perm, b0, h1);
  // layer 2: out(f32)
  k_gemm<true><<<(NN + GR - 1) / GR, 256, 0, stream>>>(h1, wt1, dis, bufA);
  k_agg<false><<<AGG_GRID, 256, 0, stream>>>(bufA, dis, row_start, row_end, csr, perm, b1, out);
}